// Round 8
// baseline (127.261 us; speedup 1.0000x reference)
//
#include <hip/hip_runtime.h>
#include <cstdint>

// Linear-chain CRF log-partition, B=64, T=4096, S=64.
// R8 = R7 resubmit (two consecutive broker/container failures; source audited
// — no hang/OOB path; unchanged to preserve the post-mortem).
// Transpose-free MFMA scan. Orientation: chains = MFMA cols, states = rows,
// with state s = 16q + 4*mt + r. The C/D fragment of lane 16q+l holds states
// 16q..16q+15 of chain l — exactly the B-operand set for the next step:
// B_kb[j] = acc[2kb+(j>>2)][j&3] is a pure in-lane register select.
// Zero LDS, zero barriers in the K-loop. NC=819 x L=5 chunks (819*5=4095),
// fwd y=1^T M_c (4 MFMA steps, 1^T E precomputed), bwd z=M_c 1 (5 steps),
// rank-1 recombination in phase2. No renorm: stores scaled by exact 2^-20,
// constant +20*819*ln2 folded into the output.

#define B_    64
#define T_    4096
#define S_    64
#define L_    5
#define NC_   819                 // 819*5 = 4095 = T_-1
#define WPB_  52                  // 16-chain wave-blocks per batch
#define LOG2E 1.44269504088896340736f
#define YSCALE 9.5367431640625e-07f   // 2^-20 exact

typedef float  f32x4  __attribute__((ext_vector_type(4)));
typedef __bf16 bf16x8 __attribute__((ext_vector_type(8)));
union U4B { uint4 u; bf16x8 b; };

// ---------------------------------------------------------------------------
// prepE: per-lane E fragments (fwd: A=E^T, bwd: A=E) in the (q,mt,r) state
// permutation, plus colsum[s] = sum_in exp(T[in][s]) = (1^T E)[s].
// ---------------------------------------------------------------------------
__global__ __launch_bounds__(64) void crf_prepE(
    const float* __restrict__ transition, uint4* __restrict__ Etab,
    float* __restrict__ colsum)
{
    const int dir = blockIdx.x, lane = threadIdx.x;
    const int q = lane >> 4, l = lane & 15;
    const int po = 16 * (l >> 2) + (l & 3);
    #pragma unroll
    for (int kb = 0; kb < 2; ++kb)
    #pragma unroll
    for (int mt = 0; mt < 4; ++mt) {
        U4B t;
        #pragma unroll
        for (int j = 0; j < 8; ++j) {
            int si = 16 * q + 8 * kb + j;       // k-index state (input)
            int so = po + 4 * mt;               // m-index state (output)
            float tv = dir ? transition[so * 64 + si] : transition[si * 64 + so];
            t.b[j] = (__bf16)exp2f(tv * LOG2E);
        }
        Etab[(dir * 64 + lane) * 8 + kb * 4 + mt] = t.u;
    }
    if (dir == 0) {
        float cs = 0.f;
        for (int i = 0; i < 64; ++i)
            cs += exp2f(transition[i * 64 + lane] * LOG2E);
        colsum[lane] = cs;
    }
}

// ---------------------------------------------------------------------------
// phase1: one wave per (dir, b, wg); 16 chains (cols) per wave.
// fwd:  y_c^T = 1^T E d1 E d2 E d3 E d4 E d5   (1^T E preloaded -> 4 MFMAs)
// bwd:  z_c   = E d1 E d2 E d3 E d4 E d5 1     (5 MFMAs)
// ---------------------------------------------------------------------------
__global__ __launch_bounds__(64, 4) void crf_phase1(
    const float* __restrict__ scores, const uint4* __restrict__ Etab,
    const float* __restrict__ colsum,
    float* __restrict__ Ybuf, float* __restrict__ Zbuf)
{
    const int wid = blockIdx.x;
    const bool bwd = wid >= (B_ * WPB_);
    const int wl = bwd ? wid - B_ * WPB_ : wid;
    const int b = wl / WPB_, wg = wl % WPB_;
    const int lane = threadIdx.x, q = lane >> 4, l = lane & 15;

    bf16x8 A[2][4];
    {
        const uint4* ep = Etab + ((bwd ? 64 : 0) + lane) * 8;
        #pragma unroll
        for (int kb = 0; kb < 2; ++kb)
        #pragma unroll
        for (int mt = 0; mt < 4; ++mt) { U4B t; t.u = ep[kb * 4 + mt]; A[kb][mt] = t.b; }
    }

    int cl = 16 * wg + l; if (cl > NC_ - 1) cl = NC_ - 1;   // padded chains clamp
    const float* ap = scores + ((size_t)b * T_ + (size_t)L_ * cl) * S_ + 16 * q;

    f32x4 acc[4];
    f32x4 R[3][4];                 // depth-3 emission prefetch ring

    auto ldq = [&](int k, f32x4* Rr) {
        const float* p = ap + k * S_;
        Rr[0] = *(const f32x4*)p;       Rr[1] = *(const f32x4*)(p + 4);
        Rr[2] = *(const f32x4*)(p + 8); Rr[3] = *(const f32x4*)(p + 12);
    };
    auto emul = [&](f32x4* Rr) {    // acc[state s][chain l] *= exp(score[t][s])
        #pragma unroll
        for (int mt = 0; mt < 4; ++mt)
            #pragma unroll
            for (int r = 0; r < 4; ++r)
                acc[mt][r] *= exp2f(Rr[mt][r] * LOG2E);
    };
    auto step = [&]() {             // acc <- E^T/E * acc (in-lane repack, no LDS)
        bf16x8 B0, B1;
        #pragma unroll
        for (int j = 0; j < 8; ++j) {
            B0[j] = (__bf16)acc[(j >> 2)][j & 3];
            B1[j] = (__bf16)acc[2 + (j >> 2)][j & 3];
        }
        #pragma unroll
        for (int mt = 0; mt < 4; ++mt) {
            f32x4 z4 = {0.f, 0.f, 0.f, 0.f};
            z4      = __builtin_amdgcn_mfma_f32_16x16x32_bf16(A[0][mt], B0, z4, 0, 0, 0);
            acc[mt] = __builtin_amdgcn_mfma_f32_16x16x32_bf16(A[1][mt], B1, z4, 0, 0, 0);
        }
    };

    if (!bwd) {
        ldq(1, R[0]); ldq(2, R[1]); ldq(3, R[2]);
        const float* cp = colsum + 16 * q;      // acc = 1^T E
        #pragma unroll
        for (int mt = 0; mt < 4; ++mt) acc[mt] = *(const f32x4*)(cp + 4 * mt);
        emul(R[0]); ldq(4, R[0]); step();
        emul(R[1]); ldq(5, R[1]); step();
        emul(R[2]); step();
        emul(R[0]); step();
        emul(R[1]);                              // trailing d5, no MFMA after
        float* ob = Ybuf + ((size_t)(b * WPB_ + wg) << 10);
        #pragma unroll
        for (int mt = 0; mt < 4; ++mt) {
            f32x4 v = acc[mt];
            #pragma unroll
            for (int r = 0; r < 4; ++r) v[r] *= YSCALE;
            *(f32x4*)(ob + ((mt * 64 + lane) << 2)) = v;
        }
    } else {
        ldq(5, R[0]); ldq(4, R[1]); ldq(3, R[2]);
        {   // z1 = E d5 1 : B = exp(em row5) directly
            bf16x8 B0, B1;
            #pragma unroll
            for (int j = 0; j < 8; ++j) {
                B0[j] = (__bf16)exp2f(R[0][(j >> 2)][j & 3] * LOG2E);
                B1[j] = (__bf16)exp2f(R[0][2 + (j >> 2)][j & 3] * LOG2E);
            }
            #pragma unroll
            for (int mt = 0; mt < 4; ++mt) {
                f32x4 z4 = {0.f, 0.f, 0.f, 0.f};
                z4      = __builtin_amdgcn_mfma_f32_16x16x32_bf16(A[0][mt], B0, z4, 0, 0, 0);
                acc[mt] = __builtin_amdgcn_mfma_f32_16x16x32_bf16(A[1][mt], B1, z4, 0, 0, 0);
            }
        }
        ldq(2, R[0]);
        emul(R[1]); ldq(1, R[1]); step();
        emul(R[2]); step();
        emul(R[0]); step();
        emul(R[1]); step();
        float* ob = Zbuf + ((size_t)(b * WPB_ + wg) << 10);
        #pragma unroll
        for (int mt = 0; mt < 4; ++mt) {
            f32x4 v = acc[mt];
            #pragma unroll
            for (int r = 0; r < 4; ++r) v[r] *= YSCALE;
            *(f32x4*)(ob + ((mt * 64 + lane) << 2)) = v;
        }
    }
}

// ---------------------------------------------------------------------------
// phase2: rank-1 recombination on fragment-ordered blocks.
// Fragment element (mt, lane=16q+l, r) = chain 16wg+l, state 16q+4mt+r.
// log2 Z = log2(a0.z_0) + sum_c [log2(y_c.zn_c) - log2(y_c.1)],
// zn_c = z_{c+1} (esink, unscaled, for c=NC-1).
// Stored z's carry 2^-20 each and are consumed exactly once each
// (z_0 in a0z0, z_1..z_{NC-1} in seams) -> compensate +20*NC_*ln2.
// ---------------------------------------------------------------------------
__global__ __launch_bounds__(512) void crf_phase2(
    const float* __restrict__ scores, const float* __restrict__ source,
    const float* __restrict__ sink,
    const float* __restrict__ Ybuf, const float* __restrict__ Zbuf,
    float* __restrict__ out)
{
    __shared__ float part[8];
    const int b = blockIdx.x;
    const int wv = threadIdx.x >> 6, lane = threadIdx.x & 63;
    const int q = lane >> 4, l = lane & 15;
    float acc = 0.f;

    for (int wg = wv; wg < WPB_; wg += 8) {
        const float* Yb = Ybuf + ((size_t)(b * WPB_ + wg) << 10);
        const float* Zb = Zbuf + ((size_t)(b * WPB_ + wg) << 10);
        f32x4 y[4], z[4], zn[4];
        #pragma unroll
        for (int mt = 0; mt < 4; ++mt) {
            y[mt] = *(const f32x4*)(Yb + ((mt * 64 + lane) << 2));
            z[mt] = *(const f32x4*)(Zb + ((mt * 64 + lane) << 2));
        }
        // z of chain+1: lane+1 within the 16-lane group; l==15 from next block
        #pragma unroll
        for (int mt = 0; mt < 4; ++mt)
            #pragma unroll
            for (int r = 0; r < 4; ++r)
                zn[mt][r] = __shfl(z[mt][r], lane + 1, 64);
        if (l == 15 && wg + 1 < WPB_) {
            #pragma unroll
            for (int mt = 0; mt < 4; ++mt)
                zn[mt] = *(const f32x4*)(Zb + 1024 + ((mt * 64 + 16 * q) << 2));
        }
        const int c = 16 * wg + l;
        if (c == NC_ - 1) {        // last chunk: zn = exp(sink), UNSCALED
            #pragma unroll
            for (int mt = 0; mt < 4; ++mt) {
                f32x4 sv = *(const f32x4*)(sink + 16 * q + 4 * mt);
                #pragma unroll
                for (int r = 0; r < 4; ++r) zn[mt][r] = exp2f(sv[r] * LOG2E);
            }
        }
        float p = 0.f, qs = 0.f;
        #pragma unroll
        for (int mt = 0; mt < 4; ++mt)
            #pragma unroll
            for (int r = 0; r < 4; ++r) {
                float ye = y[mt][r];
                p  += ye * zn[mt][r];
                qs += ye;
            }
        p  += __shfl_xor(p, 16, 64);  p  += __shfl_xor(p, 32, 64);
        qs += __shfl_xor(qs, 16, 64); qs += __shfl_xor(qs, 32, 64);
        if (q == 0 && c < NC_) acc += log2f(p) - log2f(qs);

        if (wg == 0 && l == 0) {   // a0 . z_0 term
            float s0 = 0.f;
            #pragma unroll
            for (int mt = 0; mt < 4; ++mt) {
                f32x4 sv = *(const f32x4*)(source + 16 * q + 4 * mt);
                f32x4 e0 = *(const f32x4*)(scores + (size_t)b * T_ * S_ + 16 * q + 4 * mt);
                #pragma unroll
                for (int r = 0; r < 4; ++r)
                    s0 += exp2f((sv[r] + e0[r]) * LOG2E) * z[mt][r];
            }
            s0 += __shfl_xor(s0, 16, 64); s0 += __shfl_xor(s0, 32, 64);
            if (q == 0) acc += log2f(s0);
        }
    }
    #pragma unroll
    for (int m = 32; m >= 1; m >>= 1) acc += __shfl_xor(acc, m, 64);
    if (lane == 0) part[wv] = acc;
    __syncthreads();
    if (threadIdx.x == 0) {
        float s = 0.f;
        #pragma unroll
        for (int i = 0; i < 8; ++i) s += part[i];
        // ln2*(s + 20*NC_) + ln(64)
        out[b] = 0.6931471805599453f * (s + 16380.0f) + 4.158883083359672f;
    }
}

extern "C" void kernel_launch(void* const* d_in, const int* in_sizes, int n_in,
                              void* d_out, int out_size, void* d_ws, size_t ws_size,
                              hipStream_t stream) {
    (void)in_sizes; (void)n_in; (void)out_size; (void)ws_size;
    const float* scores     = (const float*)d_in[0];
    const float* transition = (const float*)d_in[1];
    const float* source     = (const float*)d_in[2];
    const float* sink       = (const float*)d_in[3];
    float* out = (float*)d_out;

    float* Ybuf   = (float*)d_ws;                        // 64*52*1024 f32 (13.6 MB)
    float* Zbuf   = Ybuf + (size_t)B_ * WPB_ * 1024;     // 13.6 MB
    float* colsum = Zbuf + (size_t)B_ * WPB_ * 1024;     // 64 f32
    uint4* Etab   = (uint4*)(colsum + 64);               // 16 KB

    hipLaunchKernelGGL(crf_prepE, dim3(2), dim3(64), 0, stream,
                       transition, Etab, colsum);
    hipLaunchKernelGGL(crf_phase1, dim3(2 * B_ * WPB_), dim3(64), 0, stream,
                       scores, Etab, colsum, Ybuf, Zbuf);
    hipLaunchKernelGGL(crf_phase2, dim3(B_), dim3(512), 0, stream,
                       scores, source, sink, Ybuf, Zbuf, out);
}